// Round 1
// 455.533 us; speedup vs baseline: 1.0965x; 1.0965x over previous
//
#include <hip/hip_runtime.h>

typedef unsigned short ushort_t;
typedef __attribute__((ext_vector_type(8))) short bf16x8;   // 8 bf16 in 4 VGPRs
typedef __attribute__((ext_vector_type(4))) float f32x4;

#define H 512
#define E 1024
#define S 2048
#define B 32
#define NCHUNK (S / 64)   // 32 s-chunks per batch row

__device__ __forceinline__ ushort_t f2bf(float f) {
    unsigned u = __float_as_uint(f);
    unsigned r = (u + 0x7FFFu + ((u >> 16) & 1u)) >> 16;   // RNE
    return (ushort_t)r;
}

// round-half-up bf16 pack of two floats: low = bf(x), high = bf(y). 3 VALU ops.
__device__ __forceinline__ unsigned pkbf(float x, float y) {
    unsigned u0 = __float_as_uint(x) + 0x8000u;
    unsigned u1 = __float_as_uint(y) + 0x8000u;
    return __builtin_amdgcn_perm(u1, u0, 0x07060302u);   // bytes [u1.3,u1.2,u0.3,u0.2]
}

// fast tanh via hardware exp: tanh(x) = 1 - 2/(e^{2x}+1); |err| ~1e-6, fine for absmax tol
__device__ __forceinline__ float fast_tanh(float x) {
    float e = __expf(2.f * x);
    return 1.f - 2.f / (e + 1.f);
}

// hb[b][h] = hidden[b] @ Wh + ba  — split-K over 8 chunks, atomicAdd into zeroed hb
__global__ void prep_hb(const float* __restrict__ hidden, const float* __restrict__ Wa,
                        const float* __restrict__ ba, float* __restrict__ hb) {
    int b = blockIdx.x, kc = blockIdx.y, tid = threadIdx.x;
    const float* hp = hidden + b * H + kc * 64;
    float a0 = 0.f, a1 = 0.f;
    #pragma unroll 8
    for (int k = 0; k < 64; ++k) {
        float hv = hp[k];
        a0 += hv * Wa[(size_t)(kc * 64 + k) * H + tid];
        a1 += hv * Wa[(size_t)(kc * 64 + k) * H + tid + 256];
    }
    if (kc == 0) { a0 += ba[tid]; a1 += ba[tid + 256]; }
    atomicAdd(&hb[b * H + tid], a0);
    atomicAdd(&hb[b * H + tid + 256], a1);
}

// Swizzle We (= Wa[512:]) into bf16 MFMA-B-fragment order:
// wef[((kt*32+nt)*64 + lane)*8 + j] = We[kt*32 + (lane>>4)*8 + j][nt*16 + (lane&15)]
__global__ void prep_wef(const float* __restrict__ Wa, ushort_t* __restrict__ wef) {
    int g = blockIdx.x * 256 + threadIdx.x;      // 0..65535
    int kt = g >> 11, nt = (g >> 6) & 31, l = g & 63;
    int kbase = kt * 32 + ((l >> 4) << 3);
    int n = nt * 16 + (l & 15);
    #pragma unroll
    for (int j = 0; j < 8; ++j)
        wef[(size_t)g * 8 + j] = f2bf(Wa[(size_t)(H + kbase + j) * H + n]);
}

// Fused: scores -> per-chunk softmax partial (m,l,p) -> partial context (no atomics).
// K-loop: counted-vmcnt protocol (T3/T4): A staged depth-2 into 4 rotating LDS buffers
// via global_load_lds; B read straight from L2 into registers (fragment-ordered wef),
// prefetched one K-step ahead. ONE raw s_barrier per K-step, vmcnt never drained to 0.
__launch_bounds__(256, 2)
__global__ void score_kernel(const float* __restrict__ enc, const ushort_t* __restrict__ wef,
                             const float* __restrict__ hb, const float* __restrict__ v,
                             float* __restrict__ scores, float* __restrict__ mpart,
                             float* __restrict__ lpart, float* __restrict__ ctxp) {
    int sc = blockIdx.x;
    int b = blockIdx.y;
    int s0 = sc * 64;
    int tid = threadIdx.x;
    int wave = tid >> 6, lane = tid & 63;
    int q = lane >> 4, nl = lane & 15;

    __shared__ char arena[32768];          // 4 x 8KB A-buffers; aliased by epilogue
    float* sred = (float*)arena;           // [0,1024) after final barrier
    float* lds_p = (float*)arena + 256;    // [1024,1280)

    f32x4 acc[4][8] = {};
    bf16x8 bregA[8], bregB[8];

    // ---- A staging source (per lane): slot = r*8 + (chunk ^ (r&7)) xor swizzle ----
    int r0 = wave * 16 + (lane >> 3);
    int c4 = ((lane & 7) ^ (lane >> 3)) * 4;
    const float* asrc0 = enc + ((size_t)b * S + s0 + r0) * E + c4;
    const float* asrc1 = asrc0 + 8 * E;
    // ---- B fragment base (register loads from L2) ----
    const bf16x8* bsrc = (const bf16x8*)wef + (size_t)(wave * 8) * 64 + lane;

#define STAGE_A(KT)                                                                      \
    {                                                                                    \
        char* al = arena + ((KT) & 3) * 8192 + wave * 2048;                              \
        __builtin_amdgcn_global_load_lds(                                                \
            (const __attribute__((address_space(1))) unsigned*)(asrc0 + (KT) * 32),      \
            (__attribute__((address_space(3))) unsigned*)(al), 16, 0, 0);                \
        __builtin_amdgcn_global_load_lds(                                                \
            (const __attribute__((address_space(1))) unsigned*)(asrc1 + (KT) * 32),      \
            (__attribute__((address_space(3))) unsigned*)(al + 1024), 16, 0, 0);         \
    }

#define LOADB(BREG, KT)                                                                  \
    _Pragma("unroll")                                                                    \
    for (int ntl = 0; ntl < 8; ++ntl) BREG[ntl] = bsrc[(size_t)(KT) * 2048 + ntl * 64];

#define COMPUTE(KT, BREG)                                                                \
    {                                                                                    \
        const float* Ac = (const float*)(arena + ((KT) & 3) * 8192);                     \
        bf16x8 afr[4];                                                                   \
        _Pragma("unroll")                                                                \
        for (int mt = 0; mt < 4; ++mt) {                                                 \
            int r = mt * 16 + nl;                                                        \
            int sa = r * 8 + ((2 * q) ^ (nl & 7));                                       \
            int sb = r * 8 + ((2 * q + 1) ^ (nl & 7));                                   \
            float4 f0 = *(const float4*)(Ac + sa * 4);                                   \
            float4 f1 = *(const float4*)(Ac + sb * 4);                                   \
            uint4 u;                                                                     \
            u.x = pkbf(f0.x, f0.y); u.y = pkbf(f0.z, f0.w);                              \
            u.z = pkbf(f1.x, f1.y); u.w = pkbf(f1.z, f1.w);                              \
            afr[mt] = *(bf16x8*)&u;                                                      \
        }                                                                                \
        _Pragma("unroll")                                                                \
        for (int ntl = 0; ntl < 8; ++ntl) {                                              \
            _Pragma("unroll")                                                            \
            for (int mt = 0; mt < 4; ++mt)                                               \
                acc[mt][ntl] = __builtin_amdgcn_mfma_f32_16x16x32_bf16(                  \
                    afr[mt], BREG[ntl], acc[mt][ntl], 0, 0, 0);                          \
        }                                                                                \
    }

    // Prologue: A(0), A(1) in flight (depth 2), B(0) in regs.
    STAGE_A(0);
    STAGE_A(1);
    __builtin_amdgcn_sched_barrier(0);
    LOADB(bregA, 0);
    __builtin_amdgcn_sched_barrier(0);
    asm volatile("s_waitcnt vmcnt(10)" ::: "memory");   // A(0) landed; A(1)+B(0) in flight
    __builtin_amdgcn_s_barrier();
    __builtin_amdgcn_sched_barrier(0);

    // Steady state: issue A(t+2), B(t+1); compute t; wait vmcnt(10) => A(t+1) landed.
#define FULL_ITER(T, BCUR, BNEXT)                                                        \
    STAGE_A((T) + 2);                                                                    \
    __builtin_amdgcn_sched_barrier(0);                                                   \
    LOADB(BNEXT, (T) + 1);                                                               \
    COMPUTE((T), BCUR);                                                                  \
    __builtin_amdgcn_sched_barrier(0);                                                   \
    asm volatile("s_waitcnt vmcnt(10)" ::: "memory");                                    \
    __builtin_amdgcn_s_barrier();                                                        \
    __builtin_amdgcn_sched_barrier(0);

    for (int it = 0; it < 15; ++it) {
        FULL_ITER(it * 2, bregA, bregB);
        FULL_ITER(it * 2 + 1, bregB, bregA);
    }
    // t = 30: no stage left; B(31) into bregB.
    LOADB(bregB, 31);
    COMPUTE(30, bregA);
    __builtin_amdgcn_sched_barrier(0);
    asm volatile("s_waitcnt vmcnt(8)" ::: "memory");    // A(31) landed; B(31) in flight
    __builtin_amdgcn_s_barrier();
    __builtin_amdgcn_sched_barrier(0);
    // t = 31
    COMPUTE(31, bregB);
    __syncthreads();                       // all LDS reads done before arena reuse

    // Epilogue: scores for this 64-row chunk (m = mt*16+q*4+r, n = wave*128+ntl*16+nl)
    float p[16];
    #pragma unroll
    for (int i = 0; i < 16; ++i) p[i] = 0.f;
    #pragma unroll
    for (int ntl = 0; ntl < 8; ++ntl) {
        int n = wave * 128 + ntl * 16 + nl;
        float hv = hb[b * H + n];
        float vv = v[n];
        #pragma unroll
        for (int mt = 0; mt < 4; ++mt)
            #pragma unroll
            for (int r = 0; r < 4; ++r)
                p[mt * 4 + r] += vv * fast_tanh(acc[mt][ntl][r] + hv);
    }
    #pragma unroll
    for (int off = 1; off < 16; off <<= 1) {
        #pragma unroll
        for (int i = 0; i < 16; ++i) p[i] += __shfl_xor(p[i], off, 64);
    }
    if (nl == 0) {
        #pragma unroll
        for (int mt = 0; mt < 4; ++mt)
            #pragma unroll
            for (int r = 0; r < 4; ++r)
                sred[wave * 64 + mt * 16 + q * 4 + r] = p[mt * 4 + r];
    }
    __syncthreads();

    // Per-chunk softmax partial: wave 0 holds all 64 scores of this chunk.
    if (tid < 64) {
        float s = sred[tid] + sred[64 + tid] + sred[128 + tid] + sred[192 + tid];
        scores[(size_t)b * S + s0 + tid] = s;
        float m = s;
        #pragma unroll
        for (int off = 32; off; off >>= 1) m = fmaxf(m, __shfl_xor(m, off, 64));
        float pe = __expf(s - m);
        lds_p[tid] = pe;
        float l = pe;
        #pragma unroll
        for (int off = 32; off; off >>= 1) l += __shfl_xor(l, off, 64);
        if (tid == 0) { mpart[b * NCHUNK + sc] = m; lpart[b * NCHUNK + sc] = l; }
    }
    __syncthreads();

    // Partial context: ctxp[b][sc][e] = sum_{s in chunk} p_s * enc[b,s0+s,e]
    // enc tile is L2/L3-hot (just streamed through for the GEMM).
    const float* ep = enc + ((size_t)b * S + s0) * E + tid * 4;
    float cx = 0.f, cy = 0.f, cz = 0.f, cw = 0.f;
    #pragma unroll 8
    for (int s = 0; s < 64; ++s) {
        float ps = lds_p[s];
        float4 x = *(const float4*)(ep + (size_t)s * E);
        cx += ps * x.x; cy += ps * x.y; cz += ps * x.z; cw += ps * x.w;
    }
    float4 co = {cx, cy, cz, cw};
    *(float4*)(ctxp + ((size_t)(b * NCHUNK + sc)) * E + tid * 4) = co;
#undef STAGE_A
#undef LOADB
#undef COMPUTE
#undef FULL_ITER
}

// Merge 32 chunk-partials per b: global M, L; context = sum_i exp(m_i-M)*ctxp_i / L;
// weights = exp(score - M)/L. One block per b.
__global__ void combine_kernel(const float* __restrict__ scores, const float* __restrict__ mpart,
                               const float* __restrict__ lpart, const float* __restrict__ ctxp,
                               float* __restrict__ out) {
    int b = blockIdx.x, tid = threadIdx.x;
    __shared__ float sscale[NCHUNK];
    __shared__ float sml[2];
    if (tid < NCHUNK) {
        float m = mpart[b * NCHUNK + tid];
        float M = m;
        #pragma unroll
        for (int off = 16; off; off >>= 1) M = fmaxf(M, __shfl_xor(M, off, 64));
        float e = __expf(m - M);
        float l = lpart[b * NCHUNK + tid] * e;
        float L = l;
        #pragma unroll
        for (int off = 16; off; off >>= 1) L += __shfl_xor(L, off, 64);
        sscale[tid] = e;
        if (tid == 0) { sml[0] = M; sml[1] = L; }
    }
    __syncthreads();
    float M = sml[0], invL = 1.0f / sml[1];
    int e0 = tid * 4;
    float cx = 0.f, cy = 0.f, cz = 0.f, cw = 0.f;
    #pragma unroll 4
    for (int i = 0; i < NCHUNK; ++i) {
        float scv = sscale[i];
        float4 x = *(const float4*)(ctxp + ((size_t)(b * NCHUNK + i)) * E + e0);
        cx += scv * x.x; cy += scv * x.y; cz += scv * x.z; cw += scv * x.w;
    }
    float4 co = {cx * invL, cy * invL, cz * invL, cw * invL};
    *(float4*)(out + (size_t)b * E + e0) = co;
    const float* srow = scores + (size_t)b * S;
    float* wrow = out + B * E + (size_t)b * S;
    #pragma unroll
    for (int j = 0; j < 8; ++j) {
        int s = tid + j * 256;
        wrow[s] = __expf(srow[s] - M) * invL;
    }
}

extern "C" void kernel_launch(void* const* d_in, const int* in_sizes, int n_in,
                              void* d_out, int out_size, void* d_ws, size_t ws_size,
                              hipStream_t stream) {
    const float* hidden = (const float*)d_in[0];
    const float* enc    = (const float*)d_in[1];
    const float* Wa     = (const float*)d_in[2];
    const float* ba     = (const float*)d_in[3];
    const float* v      = (const float*)d_in[4];
    float* out = (float*)d_out;

    char* ws = (char*)d_ws;
    ushort_t* wef = (ushort_t*)ws;                                      // 1 MiB
    float* hb     = (float*)(ws + (1 << 20));                           // 64 KiB
    float* scores = (float*)(ws + (1 << 20) + (1 << 16));               // 256 KiB
    float* mpart  = (float*)(ws + (1 << 20) + (1 << 16) + (1 << 18));   // 4 KiB
    float* lpart  = mpart + B * NCHUNK;                                 // 4 KiB
    float* ctxp   = (float*)(ws + (1 << 20) + (1 << 16) + (1 << 18) + (1 << 14)); // 4 MiB

    hipMemsetAsync(hb, 0, B * H * sizeof(float), stream);
    prep_hb<<<dim3(B, 8), 256, 0, stream>>>(hidden, Wa, ba, hb);
    prep_wef<<<256, 256, 0, stream>>>(Wa, wef);
    score_kernel<<<dim3(NCHUNK, B), 256, 0, stream>>>(enc, wef, hb, v,
                                                      scores, mpart, lpart, ctxp);
    combine_kernel<<<B, 256, 0, stream>>>(scores, mpart, lpart, ctxp, out);
}